// Round 2
// baseline (1869.197 us; speedup 1.0000x reference)
//
#include <hip/hip_runtime.h>
#include <cstdint>
#include <cstddef>

#define BB 32
#define LL 2048
#define DD 64

typedef __attribute__((ext_vector_type(8))) short bf16x8;   // 8 bf16 = 4 VGPRs
typedef __attribute__((ext_vector_type(4))) float f32x4;    // MFMA C/D frag

__device__ inline unsigned short f2bf(float x) {
    union { float f; unsigned u; } v; v.f = x;
    unsigned r = v.u + 0x7FFFu + ((v.u >> 16) & 1u);        // RNE
    return (unsigned short)(r >> 16);
}

// ---------------------------------------------------------------------------
// Fused: S = (Q/8)·K^T (bf16 MFMA) -> mask -> p=exp(s) (UNNORMALIZED) ->
//        write p to attn, p through LDS -> O += p·V (bf16 MFMA).
// Block: 256 thr (4 waves), q-tile 128, k-tile 64. Wave w owns q rows
// [32w,32w+32) -> sP rows are wave-private (no barrier between epilogue & PV).
// Layouts (verified m89/m91/m120): A[m=lane&15][k=quad*8+j],
// B^T[n=lane&15][k=quad*8+j], C row=quad*4+reg, col=lane&15.
// LDS stride 72 bf16 = 144B -> b128 reads are 2-way (free, m136).
// ---------------------------------------------------------------------------
__global__ __launch_bounds__(256) void k_fused(
    const float* __restrict__ q, const float* __restrict__ kmat,
    const float* __restrict__ v, const int* __restrict__ diag,
    const int* __restrict__ mask, float* __restrict__ attn,
    float* __restrict__ out)
{
    __shared__ __align__(16) unsigned short sQ[128][72];
    __shared__ __align__(16) unsigned short sK[64][72];
    __shared__ __align__(16) unsigned short sVT[64][72];   // V^T: [d][k]
    __shared__ __align__(16) unsigned short sP[128][72];

    const int b    = blockIdx.y;
    const int q0   = blockIdx.x * 128;
    const int t    = threadIdx.x;
    const int w    = t >> 6;
    const int lane = t & 63;
    const int lr   = lane & 15;
    const int quad = lane >> 4;
    const int m0   = w * 32;

    // stage Q once, pre-scaled by 1/temperature
    const float* qb = q + ((size_t)(b * LL + q0)) * DD;
    #pragma unroll
    for (int i = 0; i < 8; ++i) {
        int lin = t + 256 * i;
        int row = lin >> 4, dv = lin & 15;
        float4 a = *(const float4*)(qb + (size_t)row * DD + dv * 4);
        unsigned short* dst = &sQ[row][dv * 4];
        dst[0] = f2bf(a.x * 0.125f); dst[1] = f2bf(a.y * 0.125f);
        dst[2] = f2bf(a.z * 0.125f); dst[3] = f2bf(a.w * 0.125f);
    }

    f32x4 O[2][4];
    #pragma unroll
    for (int mi = 0; mi < 2; ++mi)
        #pragma unroll
        for (int di = 0; di < 4; ++di) O[mi][di] = (f32x4){0.f, 0.f, 0.f, 0.f};

    const float* kb = kmat + (size_t)b * LL * DD;
    const float* vb = v    + (size_t)b * LL * DD;

    for (int k0 = 0; k0 < LL; k0 += 64) {
        // ---- stage K tile (natural) and V tile (transposed) as bf16 ----
        #pragma unroll
        for (int i = 0; i < 4; ++i) {
            int lin = t + 256 * i;
            int row = lin >> 4, dv = lin & 15;
            float4 a = *(const float4*)(kb + (size_t)(k0 + row) * DD + dv * 4);
            unsigned short* dst = &sK[row][dv * 4];
            dst[0] = f2bf(a.x); dst[1] = f2bf(a.y);
            dst[2] = f2bf(a.z); dst[3] = f2bf(a.w);
            float4 c = *(const float4*)(vb + (size_t)(k0 + row) * DD + dv * 4);
            sVT[dv * 4 + 0][row] = f2bf(c.x);
            sVT[dv * 4 + 1][row] = f2bf(c.y);
            sVT[dv * 4 + 2][row] = f2bf(c.z);
            sVT[dv * 4 + 3][row] = f2bf(c.w);
        }
        __syncthreads();

        // ---- QK^T MFMA: 2 m-frags x 4 n-frags, K(=d)=64 in 2 chunks ----
        f32x4 S[2][4];
        #pragma unroll
        for (int mi = 0; mi < 2; ++mi)
            #pragma unroll
            for (int ni = 0; ni < 4; ++ni) S[mi][ni] = (f32x4){0.f, 0.f, 0.f, 0.f};
        #pragma unroll
        for (int dc = 0; dc < 2; ++dc) {
            bf16x8 a0 = *(const bf16x8*)&sQ[m0 +      lr][dc * 32 + quad * 8];
            bf16x8 a1 = *(const bf16x8*)&sQ[m0 + 16 + lr][dc * 32 + quad * 8];
            #pragma unroll
            for (int ni = 0; ni < 4; ++ni) {
                bf16x8 bk = *(const bf16x8*)&sK[ni * 16 + lr][dc * 32 + quad * 8];
                S[0][ni] = __builtin_amdgcn_mfma_f32_16x16x32_bf16(a0, bk, S[0][ni], 0, 0, 0);
                S[1][ni] = __builtin_amdgcn_mfma_f32_16x16x32_bf16(a1, bk, S[1][ni], 0, 0, 0);
            }
        }

        // ---- epilogue: mask, exp (unnormalized), write attn, fill sP ----
        #pragma unroll
        for (int mi = 0; mi < 2; ++mi) {
            int rbase = m0 + mi * 16 + quad * 4;
            #pragma unroll
            for (int ni = 0; ni < 4; ++ni) {
                int gcol = k0 + ni * 16 + lr;
                size_t idx = ((size_t)(b * LL + q0 + rbase)) * LL + gcol;
                #pragma unroll
                for (int reg = 0; reg < 4; ++reg) {
                    int dm = diag[idx];
                    int mk = mask[idx];
                    float p = (dm == 0 || mk != 0) ? 0.0f : __expf(S[mi][ni][reg]);
                    attn[idx] = p;
                    sP[rbase + reg][ni * 16 + lr] = f2bf(p);
                    idx += LL;
                }
            }
        }
        // sP rows [32w,32w+32) are written and read by the SAME wave -> no
        // barrier needed here (compiler inserts lgkmcnt waits).

        // ---- PV MFMA: O += P·V, K(=keys)=64 in 2 chunks ----
        #pragma unroll
        for (int kc = 0; kc < 2; ++kc) {
            bf16x8 a0 = *(const bf16x8*)&sP[m0 +      lr][kc * 32 + quad * 8];
            bf16x8 a1 = *(const bf16x8*)&sP[m0 + 16 + lr][kc * 32 + quad * 8];
            #pragma unroll
            for (int di = 0; di < 4; ++di) {
                bf16x8 bv = *(const bf16x8*)&sVT[di * 16 + lr][kc * 32 + quad * 8];
                O[0][di] = __builtin_amdgcn_mfma_f32_16x16x32_bf16(a0, bv, O[0][di], 0, 0, 0);
                O[1][di] = __builtin_amdgcn_mfma_f32_16x16x32_bf16(a1, bv, O[1][di], 0, 0, 0);
            }
        }
        __syncthreads();   // protect sK/sVT for next iteration's staging
    }

    // write UNNORMALIZED O; k_norm rescales by 1/rowsum
    #pragma unroll
    for (int mi = 0; mi < 2; ++mi)
        #pragma unroll
        for (int di = 0; di < 4; ++di)
            #pragma unroll
            for (int reg = 0; reg < 4; ++reg)
                out[((size_t)(b * LL + q0 + m0 + mi * 16 + quad * 4 + reg)) * DD
                    + di * 16 + lr] = O[mi][di][reg];
}

// ---------------------------------------------------------------------------
// Normalize: per (b,q) row, l = sum(p); attn_row *= 1/l; out_row *= 1/l.
// ---------------------------------------------------------------------------
__global__ __launch_bounds__(256) void k_norm(
    float* __restrict__ attn, float* __restrict__ out)
{
    __shared__ float reds[4];
    const size_t row = blockIdx.x;
    float* p = attn + row * LL;
    const int t = threadIdx.x, wave = t >> 6, lane = t & 63;

    float4 x0 = ((const float4*)p)[t];
    float4 x1 = ((const float4*)p)[t + 256];
    float s = (x0.x + x0.y + x0.z + x0.w) + (x1.x + x1.y + x1.z + x1.w);
    #pragma unroll
    for (int off = 32; off >= 1; off >>= 1)
        s += __shfl_xor(s, off, 64);
    if (lane == 0) reds[wave] = s;
    __syncthreads();
    s = (reds[0] + reds[1]) + (reds[2] + reds[3]);

    const float inv = 1.0f / s;
    x0.x *= inv; x0.y *= inv; x0.z *= inv; x0.w *= inv;
    x1.x *= inv; x1.y *= inv; x1.z *= inv; x1.w *= inv;
    ((float4*)p)[t]       = x0;
    ((float4*)p)[t + 256] = x1;

    if (t < 16) {
        float4 o = ((float4*)(out + row * DD))[t];
        o.x *= inv; o.y *= inv; o.z *= inv; o.w *= inv;
        ((float4*)(out + row * DD))[t] = o;
    }
}

// ---------------------------------------------------------------------------
extern "C" void kernel_launch(void* const* d_in, const int* in_sizes, int n_in,
                              void* d_out, int out_size, void* d_ws, size_t ws_size,
                              hipStream_t stream)
{
    const float* q    = (const float*)d_in[0];
    const float* k    = (const float*)d_in[1];
    const float* v    = (const float*)d_in[2];
    const int*   diag = (const int*)d_in[3];
    const int*   mask = (const int*)d_in[4];

    float* out  = (float*)d_out;                    // [B, L, D]
    float* attn = out + (size_t)BB * LL * DD;       // [B, L, L]

    k_fused<<<dim3(LL / 128, BB), 256, 0, stream>>>(q, k, v, diag, mask, attn, out);
    k_norm <<<dim3(BB * LL),      256, 0, stream>>>(attn, out);
}